// Round 12
// baseline (364.752 us; speedup 1.0000x reference)
//
#include <hip/hip_runtime.h>

typedef int   i32x4  __attribute__((ext_vector_type(4)));
typedef int   i32x8  __attribute__((ext_vector_type(8)));
typedef float f32x4  __attribute__((ext_vector_type(4)));

// ---------- kernel 1: fused L2 normalize -> fp8 e4m3 of (x * 32 / ||row||) ----------
__global__ __launch_bounds__(256) void l2norm_fp8_kernel(const float* __restrict__ audio,
                                                         const float* __restrict__ visual,
                                                         unsigned char* __restrict__ out) {
    const int gw = blockIdx.x * 4 + (threadIdx.x >> 6);  // global row 0..24575
    const int l  = threadIdx.x & 63;
    const float* src = (gw < 16384) ? (audio + (size_t)gw * 768)
                                    : (visual + ((size_t)gw - 16384) * 768);
    const float4* p = (const float4*)src;
    float4 a = p[l], b = p[l + 64], c = p[l + 128];
    float ss = a.x * a.x + a.y * a.y + a.z * a.z + a.w * a.w
             + b.x * b.x + b.y * b.y + b.z * b.z + b.w * b.w
             + c.x * c.x + c.y * c.y + c.z * c.z + c.w * c.w;
#pragma unroll
    for (int m = 1; m < 64; m <<= 1) ss += __shfl_xor(ss, m, 64);
    const float s = 32.0f / fmaxf(sqrtf(ss), 1e-12f);
    unsigned int* o = (unsigned int*)(out + (size_t)gw * 768);
    int d0 = __builtin_amdgcn_cvt_pk_fp8_f32(a.x * s, a.y * s, 0, false);
    d0     = __builtin_amdgcn_cvt_pk_fp8_f32(a.z * s, a.w * s, d0, true);
    int d1 = __builtin_amdgcn_cvt_pk_fp8_f32(b.x * s, b.y * s, 0, false);
    d1     = __builtin_amdgcn_cvt_pk_fp8_f32(b.z * s, b.w * s, d1, true);
    int d2 = __builtin_amdgcn_cvt_pk_fp8_f32(c.x * s, c.y * s, 0, false);
    d2     = __builtin_amdgcn_cvt_pk_fp8_f32(c.z * s, c.w * s, d2, true);
    o[l] = (unsigned int)d0; o[l + 64] = (unsigned int)d1; o[l + 128] = (unsigned int)d2;
}

// ---------- kernel 2: 128x128-tile fp8 GEMM, DIRECT-FROM-GLOBAL (no LDS, no barriers)
// A: 16384x768 fp8, V: 8192x768 fp8. 256 threads = 4 waves (2 wm x 2 wn), wave tile
// 64x64, mfma_scale_16x16x128, K = 768 = 6 x 128.
// Each lane loads its fragment bytes straight from global: frag fi, lane l reads
// rows base + fi*16 + (l&15), kb = kt*128 + (l>>4)*32 (+16) -> 2x dwordx4/frag.
// No staging, no __syncthreads in the K-loop: every wave is an independent stream;
// ~150 VGPR -> 3 blocks/CU = 3 free-running wave streams per SIMD hide L2 latency
// under each other's MFMA (m114 mechanism). Traffic 2x of staged (~3.1 GB) but all
// L2-resident by block order below.
// Block order: per XCD (bx&7): colBlk = idx>>4 (outer), rowBlk = x*16 + (idx&15)
// (inner) -> A panel per XCD = 1.57 MB resident all kernel; V-tile shared by the
// 16 concurrent rowBlk blocks; working set ~2.3 MB << 4 MB L2.
// NOTE: launch_bounds (256,3): VGPR cap ~168 vs ~160 demand. If WRITE_SIZE blows
// up -> spill (R5 lesson) -> back off to (256,2).

__device__ __forceinline__ i32x8 ld_frag(const unsigned char* p) {
    i32x4 lo = *(const i32x4*)(p);
    i32x4 hi = *(const i32x4*)(p + 16);
    return __builtin_shufflevector(lo, hi, 0, 1, 2, 3, 4, 5, 6, 7);
}

__global__ __launch_bounds__(256, 3) void gemm_max_kernel(
    const unsigned char* __restrict__ A, const unsigned char* __restrict__ V,
    float* __restrict__ rowhalf) {
    __shared__ float pm[256];  // [128 rows][2 wn] epilogue only

    const int tid = threadIdx.x;
    const int l   = tid & 63;
    const int wid = tid >> 6;
    const int wm  = wid >> 1;      // 0..1 : 64-row half of A tile
    const int wn  = wid & 1;       // 0..1 : 64-col half of B tile
    const int lr  = l & 15;
    const int lg  = l >> 4;        // 0..3

    const int bx  = blockIdx.x;       // 8192 blocks
    const int x   = bx & 7;           // XCD
    const int idx = bx >> 3;          // 0..1023 within XCD
    const int colBlk = idx >> 4;      // 0..63 (outer: V-tile reused by 16 blocks)
    const int rowBlk = x * 16 + (idx & 15);  // inner: A panel resident per XCD
    const size_t aRow0 = (size_t)rowBlk * 128;
    const size_t vRow0 = (size_t)colBlk * 128;

    // per-lane fragment base pointers (frag fi: +fi*16 rows = +12288 B)
    const unsigned char* aP0 = A + (aRow0 + wm * 64 + lr) * 768 + lg * 32;
    const unsigned char* aP1 = aP0 + 12288;
    const unsigned char* aP2 = aP0 + 24576;
    const unsigned char* aP3 = aP0 + 36864;
    const unsigned char* bP0 = V + (vRow0 + wn * 64 + lr) * 768 + lg * 32;
    const unsigned char* bP1 = bP0 + 12288;
    const unsigned char* bP2 = bP0 + 24576;
    const unsigned char* bP3 = bP0 + 36864;

    f32x4 acc[4][4];
#pragma unroll
    for (int i = 0; i < 4; ++i)
#pragma unroll
        for (int j = 0; j < 4; ++j) {
            acc[i][j][0] = 0.0f; acc[i][j][1] = 0.0f;
            acc[i][j][2] = 0.0f; acc[i][j][3] = 0.0f;
        }

#pragma unroll 1
    for (int kt = 0; kt < 6; ++kt) {
        const i32x8 fa0 = ld_frag(aP0), fa1 = ld_frag(aP1);
        const i32x8 fa2 = ld_frag(aP2), fa3 = ld_frag(aP3);
        const i32x8 fb0 = ld_frag(bP0), fb1 = ld_frag(bP1);
        const i32x8 fb2 = ld_frag(bP2), fb3 = ld_frag(bP3);
        aP0 += 128; aP1 += 128; aP2 += 128; aP3 += 128;
        bP0 += 128; bP1 += 128; bP2 += 128; bP3 += 128;

        acc[0][0] = __builtin_amdgcn_mfma_scale_f32_16x16x128_f8f6f4(
            fa0, fb0, acc[0][0], 0, 0, 0, 0x7F7F7F7F, 0, 0x7F7F7F7F);
        acc[0][1] = __builtin_amdgcn_mfma_scale_f32_16x16x128_f8f6f4(
            fa0, fb1, acc[0][1], 0, 0, 0, 0x7F7F7F7F, 0, 0x7F7F7F7F);
        acc[0][2] = __builtin_amdgcn_mfma_scale_f32_16x16x128_f8f6f4(
            fa0, fb2, acc[0][2], 0, 0, 0, 0x7F7F7F7F, 0, 0x7F7F7F7F);
        acc[0][3] = __builtin_amdgcn_mfma_scale_f32_16x16x128_f8f6f4(
            fa0, fb3, acc[0][3], 0, 0, 0, 0x7F7F7F7F, 0, 0x7F7F7F7F);
        acc[1][0] = __builtin_amdgcn_mfma_scale_f32_16x16x128_f8f6f4(
            fa1, fb0, acc[1][0], 0, 0, 0, 0x7F7F7F7F, 0, 0x7F7F7F7F);
        acc[1][1] = __builtin_amdgcn_mfma_scale_f32_16x16x128_f8f6f4(
            fa1, fb1, acc[1][1], 0, 0, 0, 0x7F7F7F7F, 0, 0x7F7F7F7F);
        acc[1][2] = __builtin_amdgcn_mfma_scale_f32_16x16x128_f8f6f4(
            fa1, fb2, acc[1][2], 0, 0, 0, 0x7F7F7F7F, 0, 0x7F7F7F7F);
        acc[1][3] = __builtin_amdgcn_mfma_scale_f32_16x16x128_f8f6f4(
            fa1, fb3, acc[1][3], 0, 0, 0, 0x7F7F7F7F, 0, 0x7F7F7F7F);
        acc[2][0] = __builtin_amdgcn_mfma_scale_f32_16x16x128_f8f6f4(
            fa2, fb0, acc[2][0], 0, 0, 0, 0x7F7F7F7F, 0, 0x7F7F7F7F);
        acc[2][1] = __builtin_amdgcn_mfma_scale_f32_16x16x128_f8f6f4(
            fa2, fb1, acc[2][1], 0, 0, 0, 0x7F7F7F7F, 0, 0x7F7F7F7F);
        acc[2][2] = __builtin_amdgcn_mfma_scale_f32_16x16x128_f8f6f4(
            fa2, fb2, acc[2][2], 0, 0, 0, 0x7F7F7F7F, 0, 0x7F7F7F7F);
        acc[2][3] = __builtin_amdgcn_mfma_scale_f32_16x16x128_f8f6f4(
            fa2, fb3, acc[2][3], 0, 0, 0, 0x7F7F7F7F, 0, 0x7F7F7F7F);
        acc[3][0] = __builtin_amdgcn_mfma_scale_f32_16x16x128_f8f6f4(
            fa3, fb0, acc[3][0], 0, 0, 0, 0x7F7F7F7F, 0, 0x7F7F7F7F);
        acc[3][1] = __builtin_amdgcn_mfma_scale_f32_16x16x128_f8f6f4(
            fa3, fb1, acc[3][1], 0, 0, 0, 0x7F7F7F7F, 0, 0x7F7F7F7F);
        acc[3][2] = __builtin_amdgcn_mfma_scale_f32_16x16x128_f8f6f4(
            fa3, fb2, acc[3][2], 0, 0, 0, 0x7F7F7F7F, 0, 0x7F7F7F7F);
        acc[3][3] = __builtin_amdgcn_mfma_scale_f32_16x16x128_f8f6f4(
            fa3, fb3, acc[3][3], 0, 0, 0, 0x7F7F7F7F, 0, 0x7F7F7F7F);
    }

    // epilogue: fused row-max over this block's 128 visual cols.
    // C/D layout (16x16): col = lane&15, row = (lane>>4)*4 + reg (m89; shape-determined)
#pragma unroll
    for (int mi = 0; mi < 4; ++mi) {
#pragma unroll
        for (int j = 0; j < 4; ++j) {
            float m = fmaxf(fmaxf(acc[mi][0][j], acc[mi][1][j]),
                            fmaxf(acc[mi][2][j], acc[mi][3][j]));
            m = fmaxf(m, __shfl_xor(m, 1, 64));
            m = fmaxf(m, __shfl_xor(m, 2, 64));
            m = fmaxf(m, __shfl_xor(m, 4, 64));
            m = fmaxf(m, __shfl_xor(m, 8, 64));
            if (lr == 0) {
                const int row = wm * 64 + mi * 16 + lg * 4 + j;
                pm[row * 2 + wn] = m;
            }
        }
    }
    __syncthreads();
    if (tid < 128) {
        float m = fmaxf(pm[tid * 2], pm[tid * 2 + 1]);
        rowhalf[(size_t)colBlk * 16384 + aRow0 + tid] = m;
    }
}

// ---------- kernel 3: combine halves (max) + mean over 512 rows -> clip_sims ----------
// folds 1/temp (x10), 1/512 mean, and 1/1024 fp8 pre-scale compensation (32*32).
__global__ __launch_bounds__(256) void reduce_mean_kernel(const float* __restrict__ rh,
                                                          float* __restrict__ clip) {
    const int b = blockIdx.x >> 5;
    const int c = blockIdx.x & 31;
    const int t = threadIdx.x;
    const float* p0 = rh + (size_t)(c * 2) * 16384 + (size_t)b * 512;
    const float* p1 = p0 + 16384;
    float s = fmaxf(p0[t], p1[t]) + fmaxf(p0[t + 256], p1[t + 256]);
#pragma unroll
    for (int m = 1; m < 64; m <<= 1) s += __shfl_xor(s, m, 64);
    __shared__ float wsum[4];
    if ((t & 63) == 0) wsum[t >> 6] = s;
    __syncthreads();
    if (t == 0)
        clip[b * 32 + c] = (wsum[0] + wsum[1] + wsum[2] + wsum[3]) * (1.0f / (51.2f * 1024.0f));
}

// ---------- kernel 4: log-softmax both ways on 32x32 + scalar loss ----------
__global__ __launch_bounds__(1024) void finalize_kernel(const float* __restrict__ clip,
                                                        float* __restrict__ out) {
    __shared__ float cs[32][33];
    __shared__ float rlse[32], clse[32];
    const int t = threadIdx.x;
    const int b = t >> 5, c = t & 31;
    cs[b][c] = clip[b * 32 + c];
    __syncthreads();
    if (t < 32) {
        float mx = -1e30f;
        for (int j = 0; j < 32; ++j) mx = fmaxf(mx, cs[t][j]);
        float s = 0.0f;
        for (int j = 0; j < 32; ++j) s += expf(cs[t][j] - mx);
        rlse[t] = mx + logf(s);
    } else if (t < 64) {
        const int cc = t - 32;
        float mx = -1e30f;
        for (int j = 0; j < 32; ++j) mx = fmaxf(mx, cs[j][cc]);
        float s = 0.0f;
        for (int j = 0; j < 32; ++j) s += expf(cs[j][cc] - mx);
        clse[cc] = mx + logf(s);
    }
    __syncthreads();
    if (t == 0) {
        float L = 0.0f;
        for (int i = 0; i < 32; ++i)
            L += -0.5f * (2.0f * cs[i][i] - rlse[i] - clse[i]);
        out[0] = L * (1.0f / 32.0f);
    }
}

extern "C" void kernel_launch(void* const* d_in, const int* in_sizes, int n_in,
                              void* d_out, int out_size, void* d_ws, size_t ws_size,
                              hipStream_t stream) {
    const float* audio  = (const float*)d_in[0];   // (32, 512, 768) f32
    const float* visual = (const float*)d_in[1];   // (32, 256, 768) f32

    unsigned char* aN = (unsigned char*)d_ws;                   // 16384*768 fp8
    unsigned char* vN = aN + (size_t)16384 * 768;               // 8192*768 fp8
    float* rowhalf = (float*)(vN + (size_t)8192 * 768);         // 64*16384 f32
    float* clip    = rowhalf + (size_t)64 * 16384;              // 1024 f32
    float* out     = (float*)d_out;

    l2norm_fp8_kernel<<<6144, 256, 0, stream>>>(audio, visual, aN);
    gemm_max_kernel<<<8192, 256, 0, stream>>>(aN, vN, rowhalf);
    reduce_mean_kernel<<<1024, 256, 0, stream>>>(rowhalf, clip);
    finalize_kernel<<<1, 1024, 0, stream>>>(clip, out);
}

// Round 13
// 122.840 us; speedup vs baseline: 2.9693x; 2.9693x over previous
//
#include <hip/hip_runtime.h>

#define GLOBAL_AS __attribute__((address_space(1)))
#define LDS_AS    __attribute__((address_space(3)))

typedef int   i32x4  __attribute__((ext_vector_type(4)));
typedef int   i32x8  __attribute__((ext_vector_type(8)));
typedef float f32x4  __attribute__((ext_vector_type(4)));

// ---------- fp4 e2m1 encode: values {0,.5,1,1.5,2,3,4,6}, round-to-nearest ----------
__device__ __forceinline__ unsigned int fp4_nib(float v) {
    float a = fabsf(v);
    unsigned int m;
    if      (a < 0.25f) m = 0;
    else if (a < 0.75f) m = 1;
    else if (a < 1.25f) m = 2;
    else if (a < 1.75f) m = 3;
    else if (a < 2.5f)  m = 4;
    else if (a < 3.5f)  m = 5;
    else if (a < 5.0f)  m = 6;
    else                m = 7;
    return m | (v < 0.0f ? 8u : 0u);
}

// ---------- kernel 1: fused L2 normalize -> fp4 of (x * 32 / ||row||) ----------
// out rows: 768 elts = 384 B (2 elts/byte, elt 2i = low nibble).
__global__ __launch_bounds__(256) void l2norm_fp4_kernel(const float* __restrict__ audio,
                                                         const float* __restrict__ visual,
                                                         unsigned char* __restrict__ out) {
    const int gw = blockIdx.x * 4 + (threadIdx.x >> 6);  // global row 0..24575
    const int l  = threadIdx.x & 63;
    const float* src = (gw < 16384) ? (audio + (size_t)gw * 768)
                                    : (visual + ((size_t)gw - 16384) * 768);
    const float4* p = (const float4*)src;
    float4 a = p[l], b = p[l + 64], c = p[l + 128];
    float ss = a.x * a.x + a.y * a.y + a.z * a.z + a.w * a.w
             + b.x * b.x + b.y * b.y + b.z * b.z + b.w * b.w
             + c.x * c.x + c.y * c.y + c.z * c.z + c.w * c.w;
#pragma unroll
    for (int m = 1; m < 64; m <<= 1) ss += __shfl_xor(ss, m, 64);
    const float s = 32.0f / fmaxf(sqrtf(ss), 1e-12f);
    unsigned short* o = (unsigned short*)(out + (size_t)gw * 384);
    unsigned short u0 = (unsigned short)(fp4_nib(a.x * s) | (fp4_nib(a.y * s) << 4) |
                                         (fp4_nib(a.z * s) << 8) | (fp4_nib(a.w * s) << 12));
    unsigned short u1 = (unsigned short)(fp4_nib(b.x * s) | (fp4_nib(b.y * s) << 4) |
                                         (fp4_nib(b.z * s) << 8) | (fp4_nib(b.w * s) << 12));
    unsigned short u2 = (unsigned short)(fp4_nib(c.x * s) | (fp4_nib(c.y * s) << 4) |
                                         (fp4_nib(c.z * s) << 8) | (fp4_nib(c.w * s) << 12));
    o[l] = u0; o[l + 64] = u1; o[l + 128] = u2;
}

// ---------- kernel 2: 128x128-tile MX-fp4 GEMM (mfma_scale 16x16x128, fmt=4) -------
// R9's verified structure unchanged: 256 threads (4 waves, 2wm x 2wn), wave tile
// 64x64, single-buffered LDS, 2 barriers/K-tile, compiler-managed waits,
// streaming (O1) block order. K = 768 = 6 x BK(128); BK = 64 B/row at fp4.
// LDS 16 KiB/tile, frag-slot layout: granule s = fi*64 + lane holds element
//   (row = fi*16 + (lane&15), K-bytes (lane>>4)*16 .. +15)  [32 fp4 K-elts/lane]
// -> read = ONE ds_read_b128 at fi*1024 + lane*16 (lane-linear, 0 conflicts);
// staging dest linear tid*16; source row = q*64 + (tid>>6)*16 + (tid&15),
// kb = ((tid>>4)&3)*16  -> wave covers 16 rows x contiguous 64 B (16 full lines).
// MFMA: cbsz=4, blgp=4 (FP4); payload in regs [0:3] of the v8i32 operand.
// NOTE: keep launch_bounds min-waves at 3 (R5 lesson: over-capping spills the
// accumulator -> 8 GB scratch traffic, 5.5x slower).

__device__ __forceinline__ i32x8 rd_frag4(const char* p) {
    i32x4 d = *(const i32x4*)(p);
    const i32x4 z = {0, 0, 0, 0};
    return __builtin_shufflevector(d, z, 0, 1, 2, 3, 4, 5, 6, 7);
}

__global__ __launch_bounds__(256, 3) void gemm_max_kernel(
    const unsigned char* __restrict__ A, const unsigned char* __restrict__ V,
    float* __restrict__ rowhalf) {
    __shared__ __align__(1024) char smem[16384];

    const int tid = threadIdx.x;
    const int l   = tid & 63;
    const int wid = tid >> 6;
    const int wm  = wid >> 1;      // 0..1 : 64-row half of A tile
    const int wn  = wid & 1;       // 0..1 : 64-col half of B tile
    const int lr  = l & 15;
    const int lg  = l >> 4;        // 0..3

    // O1 streaming block order (R9-measured fastest; O2 L2-sharing = +33 us)
    const int bx  = blockIdx.x;                   // 8192 blocks, %8==0 -> bijective
    const int swz = (bx & 7) * 1024 + (bx >> 3);  // XCD-aware swizzle
    const int rowBlk = swz >> 6;                  // 0..127
    const int colBlk = swz & 63;                  // 0..63 (clip = colBlk>>1)
    const size_t aRow0 = (size_t)rowBlk * 128;
    const size_t vRow0 = (size_t)colBlk * 128;

    // staging source (frag-slot inverse; see header). Row stride 384 B (fp4).
    const int rowT = (tid >> 6) * 16 + (tid & 15);      // 0..31 (q adds 64)
    const int kbT  = ((tid >> 4) & 3) * 16;             // 0..48
    const unsigned char* aStage = A + (aRow0 + rowT) * 384 + kbT;
    const unsigned char* vStage = V + (vRow0 + rowT) * 384 + kbT;

    // reader bases: one b128 per frag at fi*1024 + l*16
    const int aBase = wm * 4096 + l * 16;           // + mi*1024
    const int bBase = 8192 + wn * 4096 + l * 16;    // + ni*1024

    f32x4 acc[4][4];
#pragma unroll
    for (int i = 0; i < 4; ++i)
#pragma unroll
        for (int j = 0; j < 4; ++j) {
            acc[i][j][0] = 0.0f; acc[i][j][1] = 0.0f;
            acc[i][j][2] = 0.0f; acc[i][j][3] = 0.0f;
        }

#pragma unroll 1
    for (int kt = 0; kt < 6; ++kt) {
        __syncthreads();  // previous tile's reads done before overwrite
        const size_t ko = (size_t)kt * 64;
        // A: 8 KB = 2 chunks (q=0,1 -> +q*64 rows = +q*24576 B src, +q*4096 dest)
        __builtin_amdgcn_global_load_lds((GLOBAL_AS void*)(aStage + ko),
                                         (LDS_AS void*)(smem + tid * 16), 16, 0, 0);
        __builtin_amdgcn_global_load_lds((GLOBAL_AS void*)(aStage + ko + 24576),
                                         (LDS_AS void*)(smem + 4096 + tid * 16), 16, 0, 0);
        __builtin_amdgcn_global_load_lds((GLOBAL_AS void*)(vStage + ko),
                                         (LDS_AS void*)(smem + 8192 + tid * 16), 16, 0, 0);
        __builtin_amdgcn_global_load_lds((GLOBAL_AS void*)(vStage + ko + 24576),
                                         (LDS_AS void*)(smem + 12288 + tid * 16), 16, 0, 0);
        __syncthreads();  // compiler drains vmcnt(0) before barrier -> tile ready

        i32x8 fb[4];
#pragma unroll
        for (int ni = 0; ni < 4; ++ni) fb[ni] = rd_frag4(smem + bBase + ni * 1024);
#pragma unroll
        for (int mi = 0; mi < 4; ++mi) {
            const i32x8 fav = rd_frag4(smem + aBase + mi * 1024);
#pragma unroll
            for (int ni = 0; ni < 4; ++ni)
                acc[mi][ni] = __builtin_amdgcn_mfma_scale_f32_16x16x128_f8f6f4(
                    fav, fb[ni], acc[mi][ni], 4, 4, 0, 0x7F7F7F7F, 0, 0x7F7F7F7F);
        }
    }

    // epilogue: fused row-max over this block's 128 visual cols.
    // C/D layout (16x16): col = lane&15, row = (lane>>4)*4 + reg (m89; shape-determined)
    __syncthreads();
    float* pm = (float*)smem;  // [128 rows][2 wn]
#pragma unroll
    for (int mi = 0; mi < 4; ++mi) {
#pragma unroll
        for (int j = 0; j < 4; ++j) {
            float m = fmaxf(fmaxf(acc[mi][0][j], acc[mi][1][j]),
                            fmaxf(acc[mi][2][j], acc[mi][3][j]));
            m = fmaxf(m, __shfl_xor(m, 1, 64));
            m = fmaxf(m, __shfl_xor(m, 2, 64));
            m = fmaxf(m, __shfl_xor(m, 4, 64));
            m = fmaxf(m, __shfl_xor(m, 8, 64));
            if (lr == 0) {
                const int row = wm * 64 + mi * 16 + lg * 4 + j;
                pm[row * 2 + wn] = m;
            }
        }
    }
    __syncthreads();
    if (tid < 128) {
        float m = fmaxf(pm[tid * 2], pm[tid * 2 + 1]);
        rowhalf[(size_t)colBlk * 16384 + aRow0 + tid] = m;
    }
}

// ---------- kernel 3: combine halves (max) + mean over 512 rows -> clip_sims ----------
// folds 1/temp (x10), 1/512 mean, and 1/1024 fp4 pre-scale compensation (32*32).
__global__ __launch_bounds__(256) void reduce_mean_kernel(const float* __restrict__ rh,
                                                          float* __restrict__ clip) {
    const int b = blockIdx.x >> 5;
    const int c = blockIdx.x & 31;
    const int t = threadIdx.x;
    const float* p0 = rh + (size_t)(c * 2) * 16384 + (size_t)b * 512;
    const float* p1 = p0 + 16384;
    float s = fmaxf(p0[t], p1[t]) + fmaxf(p0[t + 256], p1[t + 256]);
#pragma unroll
    for (int m = 1; m < 64; m <<= 1) s += __shfl_xor(s, m, 64);
    __shared__ float wsum[4];
    if ((t & 63) == 0) wsum[t >> 6] = s;
    __syncthreads();
    if (t == 0)
        clip[b * 32 + c] = (wsum[0] + wsum[1] + wsum[2] + wsum[3]) * (1.0f / (51.2f * 1024.0f));
}

// ---------- kernel 4: log-softmax both ways on 32x32 + scalar loss ----------
__global__ __launch_bounds__(1024) void finalize_kernel(const float* __restrict__ clip,
                                                        float* __restrict__ out) {
    __shared__ float cs[32][33];
    __shared__ float rlse[32], clse[32];
    const int t = threadIdx.x;
    const int b = t >> 5, c = t & 31;
    cs[b][c] = clip[b * 32 + c];
    __syncthreads();
    if (t < 32) {
        float mx = -1e30f;
        for (int j = 0; j < 32; ++j) mx = fmaxf(mx, cs[t][j]);
        float s = 0.0f;
        for (int j = 0; j < 32; ++j) s += expf(cs[t][j] - mx);
        rlse[t] = mx + logf(s);
    } else if (t < 64) {
        const int cc = t - 32;
        float mx = -1e30f;
        for (int j = 0; j < 32; ++j) mx = fmaxf(mx, cs[j][cc]);
        float s = 0.0f;
        for (int j = 0; j < 32; ++j) s += expf(cs[j][cc] - mx);
        clse[cc] = mx + logf(s);
    }
    __syncthreads();
    if (t == 0) {
        float L = 0.0f;
        for (int i = 0; i < 32; ++i)
            L += -0.5f * (2.0f * cs[i][i] - rlse[i] - clse[i]);
        out[0] = L * (1.0f / 32.0f);
    }
}

extern "C" void kernel_launch(void* const* d_in, const int* in_sizes, int n_in,
                              void* d_out, int out_size, void* d_ws, size_t ws_size,
                              hipStream_t stream) {
    const float* audio  = (const float*)d_in[0];   // (32, 512, 768) f32
    const float* visual = (const float*)d_in[1];   // (32, 256, 768) f32

    unsigned char* aN = (unsigned char*)d_ws;                   // 16384*384 fp4
    unsigned char* vN = aN + (size_t)16384 * 384;               // 8192*384 fp4
    float* rowhalf = (float*)(vN + (size_t)8192 * 384);         // 64*16384 f32
    float* clip    = rowhalf + (size_t)64 * 16384;              // 1024 f32
    float* out     = (float*)d_out;

    l2norm_fp4_kernel<<<6144, 256, 0, stream>>>(audio, visual, aN);
    gemm_max_kernel<<<8192, 256, 0, stream>>>(aN, vN, rowhalf);
    reduce_mean_kernel<<<1024, 256, 0, stream>>>(rowhalf, clip);
    finalize_kernel<<<1, 1024, 0, stream>>>(clip, out);
}